// Round 1
// baseline (190.339 us; speedup 1.0000x reference)
//
#include <hip/hip_runtime.h>
#include <math.h>

#define NROWS 16384
#define DD 16
#define HH 128
#define JPT 4
#define TK 256

__device__ __forceinline__ float softplus_f(float x) {
    // stable: max(x,0) + log1p(exp(-|x|))
    return fmaxf(x, 0.0f) + log1pf(__expf(-fabsf(x)));
}

__global__ __launch_bounds__(256) void prep_kernel(
    const float* __restrict__ inputs,
    const float* __restrict__ W1, const float* __restrict__ b1,
    const float* __restrict__ Wm, const float* __restrict__ bm,
    const float* __restrict__ Ws, const float* __restrict__ bs,
    float* __restrict__ samples, float* __restrict__ hvals,
    float* __restrict__ acc)
{
    __shared__ float sW1[DD * HH], sWm[HH * DD], sWs[HH * DD];
    __shared__ float sb1[HH], sbm[DD], sbs[DD];
    int t = threadIdx.x;
    for (int i = t; i < DD * HH; i += 256) {
        sW1[i] = W1[i]; sWm[i] = Wm[i]; sWs[i] = Ws[i];
    }
    if (t < HH) sb1[t] = b1[t];
    if (t < DD) { sbm[t] = bm[t]; sbs[t] = bs[t]; }
    __syncthreads();

    int row = blockIdx.x * 256 + t;
    const float* rp = inputs + row * (1 + 2 * DD);
    float step = rp[0];
    float x[DD], m[DD], sc[DD];
    #pragma unroll
    for (int d = 0; d < DD; ++d) x[d] = rp[1 + d];
    #pragma unroll
    for (int d = 0; d < DD; ++d) { m[d] = sbm[d]; sc[d] = sbs[d]; }

    for (int u = 0; u < HH; ++u) {
        float hv = sb1[u];
        #pragma unroll
        for (int d = 0; d < DD; ++d) hv = fmaf(x[d], sW1[d * HH + u], hv);
        hv = fmaxf(hv, 0.0f);
        #pragma unroll
        for (int d = 0; d < DD; ++d) m[d] = fmaf(hv, sWm[u * DD + d], m[d]);
        #pragma unroll
        for (int d = 0; d < DD; ++d) sc[d] = fmaf(hv, sWs[u * DD + d], sc[d]);
    }

    float ss = sqrtf(step);
    float r2 = 0.0f;
    #pragma unroll
    for (int d = 0; d < DD; ++d) {
        float sp = softplus_f(sc[d]) + 0.001f;
        float smp = (rp[1 + DD + d] - (x[d] + step * m[d])) / (ss * sp);
        samples[row * DD + d] = smp;
        r2 = fmaf(smp, smp, r2);
    }
    hvals[row] = -0.5f * r2;

    float t1 = __expf(-0.25f * r2);
    for (int off = 32; off > 0; off >>= 1) t1 += __shfl_down(t1, off);
    __shared__ float red[4];
    if ((t & 63) == 0) red[t >> 6] = t1;
    __syncthreads();
    if (t == 0) atomicAdd(&acc[1], red[0] + red[1] + red[2] + red[3]);
}

__global__ __launch_bounds__(256) void pair_kernel(
    const float* __restrict__ samples, const float* __restrict__ hvals,
    float* __restrict__ acc)
{
    __shared__ float sk[TK * DD];
    __shared__ float shk[TK];
    int t = threadIdx.x;
    int jb = blockIdx.x;   // 0..15
    int kb = blockIdx.y;   // 0..63

    float sj[JPT][DD], hj[JPT], sum[JPT];
    #pragma unroll
    for (int jj = 0; jj < JPT; ++jj) {
        int j = jb * (JPT * 256) + jj * 256 + t;
        #pragma unroll
        for (int d = 0; d < DD; ++d) sj[jj][d] = samples[j * DD + d];
        hj[jj] = hvals[j];
        sum[jj] = 0.0f;
    }

    // stage k-tile into LDS
    {
        int k = kb * TK + t;
        const float4* src = (const float4*)(samples + k * DD);
        float4* dst = (float4*)(sk + t * DD);
        #pragma unroll
        for (int c = 0; c < 4; ++c) dst[c] = src[c];
        shk[t] = hvals[k];
    }
    __syncthreads();

    for (int kk = 0; kk < TK; ++kk) {
        float hk = shk[kk];
        const float4* sp4 = (const float4*)(sk + kk * DD);
        float4 a = sp4[0], b = sp4[1], c = sp4[2], dq = sp4[3];
        float kv[16] = {a.x, a.y, a.z, a.w, b.x, b.y, b.z, b.w,
                        c.x, c.y, c.z, c.w, dq.x, dq.y, dq.z, dq.w};
        #pragma unroll
        for (int jj = 0; jj < JPT; ++jj) {
            float arg = hj[jj] + hk;
            #pragma unroll
            for (int d = 0; d < DD; ++d) arg = fmaf(sj[jj][d], kv[d], arg);
            sum[jj] += __expf(arg);
        }
    }

    float v = sum[0] + sum[1] + sum[2] + sum[3];
    for (int off = 32; off > 0; off >>= 1) v += __shfl_down(v, off);
    __shared__ float red[4];
    if ((t & 63) == 0) red[t >> 6] = v;
    __syncthreads();
    if (t == 0) atomicAdd(&acc[0], red[0] + red[1] + red[2] + red[3]);
}

__global__ void final_kernel(const float* __restrict__ acc, float* __restrict__ out) {
    float n = (float)NROWS;
    out[0] = acc[0] / n - 0.0078125f * acc[1] + n * (1.0f / 6561.0f);
}

extern "C" void kernel_launch(void* const* d_in, const int* in_sizes, int n_in,
                              void* d_out, int out_size, void* d_ws, size_t ws_size,
                              hipStream_t stream)
{
    const float* inputs = (const float*)d_in[0];
    const float* W1 = (const float*)d_in[1];
    const float* b1 = (const float*)d_in[2];
    const float* Wm = (const float*)d_in[3];
    const float* bm = (const float*)d_in[4];
    const float* Ws = (const float*)d_in[5];
    const float* bs = (const float*)d_in[6];

    float* acc     = (float*)d_ws;                                  // 2 floats used
    float* hvals   = (float*)((char*)d_ws + 256);                   // NROWS floats
    float* samples = (float*)((char*)d_ws + 256 + NROWS * 4);       // NROWS*16 floats

    hipMemsetAsync(d_ws, 0, 256, stream);
    prep_kernel<<<NROWS / 256, 256, 0, stream>>>(inputs, W1, b1, Wm, bm, Ws, bs,
                                                 samples, hvals, acc);
    pair_kernel<<<dim3(16, 64), 256, 0, stream>>>(samples, hvals, acc);
    final_kernel<<<1, 1, 0, stream>>>(acc, (float*)d_out);
}

// Round 2
// 132.937 us; speedup vs baseline: 1.4318x; 1.4318x over previous
//
#include <hip/hip_runtime.h>
#include <math.h>

#define NROWS 16384
#define DD 16
#define HH 128
#define JPT 4
#define TK 256
#define NTILE 16        // 16 j-tiles of 1024 rows
#define L2E 1.4426950408889634f

__device__ __forceinline__ float softplus_f(float x) {
    return fmaxf(x, 0.0f) + log1pf(__expf(-fabsf(x)));
}

__device__ __forceinline__ float exp2_fast(float x) {
    float r;
    asm("v_exp_f32 %0, %1" : "=v"(r) : "v"(x));
    return r;
}

// 64 threads/block, 256 blocks: one row per thread.
__global__ __launch_bounds__(64) void prep_kernel(
    const float* __restrict__ inputs,
    const float* __restrict__ W1, const float* __restrict__ b1,
    const float* __restrict__ Wm, const float* __restrict__ bm,
    const float* __restrict__ Ws, const float* __restrict__ bs,
    float* __restrict__ samples, float* __restrict__ hvals,
    float* __restrict__ acc)
{
    __shared__ float sW1[DD * HH], sWm[HH * DD], sWs[HH * DD];
    __shared__ float sb1[HH], sbm[DD], sbs[DD];
    int t = threadIdx.x;
    for (int i = t; i < DD * HH; i += 64) {
        sW1[i] = W1[i]; sWm[i] = Wm[i]; sWs[i] = Ws[i];
    }
    for (int i = t; i < HH; i += 64) sb1[i] = b1[i];
    if (t < DD) { sbm[t] = bm[t]; sbs[t] = bs[t]; }
    __syncthreads();

    int row = blockIdx.x * 64 + t;
    const float* rp = inputs + row * (1 + 2 * DD);
    float step = rp[0];
    float x[DD], m[DD], sc[DD];
    #pragma unroll
    for (int d = 0; d < DD; ++d) x[d] = rp[1 + d];
    #pragma unroll
    for (int d = 0; d < DD; ++d) { m[d] = sbm[d]; sc[d] = sbs[d]; }

    for (int u = 0; u < HH; ++u) {
        float hv = sb1[u];
        #pragma unroll
        for (int d = 0; d < DD; ++d) hv = fmaf(x[d], sW1[d * HH + u], hv);
        hv = fmaxf(hv, 0.0f);
        #pragma unroll
        for (int d = 0; d < DD; ++d) m[d] = fmaf(hv, sWm[u * DD + d], m[d]);
        #pragma unroll
        for (int d = 0; d < DD; ++d) sc[d] = fmaf(hv, sWs[u * DD + d], sc[d]);
    }

    float ss = sqrtf(step);
    float r2 = 0.0f;
    #pragma unroll
    for (int d = 0; d < DD; ++d) {
        float sp = softplus_f(sc[d]) + 0.001f;
        float smp = (rp[1 + DD + d] - (x[d] + step * m[d])) / (ss * sp);
        samples[row * DD + d] = smp;
        r2 = fmaf(smp, smp, r2);
    }
    hvals[row] = -0.5f * r2 * L2E;     // pre-scaled for base-2 exp

    float t1 = __expf(-0.25f * r2);
    #pragma unroll
    for (int off = 32; off > 0; off >>= 1) t1 += __shfl_down(t1, off);
    if (t == 0) atomicAdd(&acc[1], t1);
}

// Symmetric tiling: 16 tiles of 1024 rows. Blocks cover (a,b) with a<=b,
// each split into 4 k-chunks of 256. Weight 2 for a<b, 1 for a==b.
__global__ __launch_bounds__(256, 2) void pair_kernel(
    const float* __restrict__ samples, const float* __restrict__ hvals,
    float* __restrict__ acc)
{
    __shared__ float sk[TK * DD];
    __shared__ float shk[TK];
    int t = threadIdx.x;

    int bx = blockIdx.x;
    int p = bx >> 2, chunk = bx & 3;
    int a = 0;
    while (p >= NTILE - a) { p -= NTILE - a; ++a; }
    int b = a + p;

    float sj[JPT][DD], hj[JPT], sum[JPT];
    #pragma unroll
    for (int jj = 0; jj < JPT; ++jj) {
        int j = a * 1024 + jj * 256 + t;
        #pragma unroll
        for (int d = 0; d < DD; ++d) sj[jj][d] = samples[j * DD + d] * L2E;
        hj[jj] = hvals[j];
        sum[jj] = 0.0f;
    }

    {
        int k = b * 1024 + chunk * 256 + t;
        const float4* src = (const float4*)(samples + k * DD);
        float4* dst = (float4*)(sk + t * DD);
        #pragma unroll
        for (int c = 0; c < 4; ++c) dst[c] = src[c];
        shk[t] = hvals[k];
    }
    __syncthreads();

    #pragma unroll 2
    for (int kk = 0; kk < TK; ++kk) {
        float hk = shk[kk];
        const float4* sp4 = (const float4*)(sk + kk * DD);
        float4 q0 = sp4[0], q1 = sp4[1], q2 = sp4[2], q3 = sp4[3];
        float kv[16] = {q0.x, q0.y, q0.z, q0.w, q1.x, q1.y, q1.z, q1.w,
                        q2.x, q2.y, q2.z, q2.w, q3.x, q3.y, q3.z, q3.w};
        #pragma unroll
        for (int jj = 0; jj < JPT; ++jj) {
            float arg = hj[jj] + hk;
            #pragma unroll
            for (int d = 0; d < DD; ++d) arg = fmaf(sj[jj][d], kv[d], arg);
            sum[jj] += exp2_fast(arg);
        }
    }

    float v = sum[0] + sum[1] + sum[2] + sum[3];
    #pragma unroll
    for (int off = 32; off > 0; off >>= 1) v += __shfl_down(v, off);
    __shared__ float red[4];
    if ((t & 63) == 0) red[t >> 6] = v;
    __syncthreads();
    if (t == 0) {
        float w = (a == b) ? 1.0f : 2.0f;
        atomicAdd(&acc[0], w * (red[0] + red[1] + red[2] + red[3]));
    }
}

__global__ void final_kernel(const float* __restrict__ acc, float* __restrict__ out) {
    float n = (float)NROWS;
    out[0] = acc[0] / n - 0.0078125f * acc[1] + n * (1.0f / 6561.0f);
}

extern "C" void kernel_launch(void* const* d_in, const int* in_sizes, int n_in,
                              void* d_out, int out_size, void* d_ws, size_t ws_size,
                              hipStream_t stream)
{
    const float* inputs = (const float*)d_in[0];
    const float* W1 = (const float*)d_in[1];
    const float* b1 = (const float*)d_in[2];
    const float* Wm = (const float*)d_in[3];
    const float* bm = (const float*)d_in[4];
    const float* Ws = (const float*)d_in[5];
    const float* bs = (const float*)d_in[6];

    float* acc     = (float*)d_ws;
    float* hvals   = (float*)((char*)d_ws + 256);
    float* samples = (float*)((char*)d_ws + 256 + NROWS * 4);

    hipMemsetAsync(d_ws, 0, 256, stream);
    prep_kernel<<<256, 64, 0, stream>>>(inputs, W1, b1, Wm, bm, Ws, bs,
                                        samples, hvals, acc);
    int npairs = NTILE * (NTILE + 1) / 2;           // 136
    pair_kernel<<<npairs * 4, 256, 0, stream>>>(samples, hvals, acc);
    final_kernel<<<1, 1, 0, stream>>>(acc, (float*)d_out);
}

// Round 3
// 100.091 us; speedup vs baseline: 1.9017x; 1.3282x over previous
//
#include <hip/hip_runtime.h>
#include <math.h>

#define NROWS 16384
#define DD 16
#define HH 128
#define JPT 4
#define TK 128
#define CHUNKS 8
#define NTILE 16        // 16 j-tiles of 1024 rows
#define L2E 1.4426950408889634f

__device__ __forceinline__ float softplus_f(float x) {
    return fmaxf(x, 0.0f) + log1pf(__expf(-fabsf(x)));
}

__device__ __forceinline__ float exp2_fast(float x) {
    float r;
    asm("v_exp_f32 %0, %1" : "=v"(r) : "v"(x));
    return r;
}

// 256 threads = 4 waves per block; 64 rows/block; wave w handles hidden units
// [w*32, (w+1)*32); partial m/sc reduced via LDS in [d][tid] layout (conflict-free).
__global__ __launch_bounds__(256) void prep_kernel(
    const float* __restrict__ inputs,
    const float* __restrict__ W1, const float* __restrict__ b1,
    const float* __restrict__ Wm, const float* __restrict__ bm,
    const float* __restrict__ Ws, const float* __restrict__ bs,
    float* __restrict__ samples, float* __restrict__ hvals,
    float* __restrict__ acc)
{
    __shared__ float sW1[DD * HH], sWm[HH * DD], sWs[HH * DD];
    __shared__ float sb1[HH];
    __shared__ float mpart[DD][256], spart[DD][256];
    int tid = threadIdx.x;
    for (int i = tid; i < DD * HH; i += 256) {
        sW1[i] = W1[i]; sWm[i] = Wm[i]; sWs[i] = Ws[i];
    }
    if (tid < HH) sb1[tid] = b1[tid];
    __syncthreads();

    int t = tid & 63, w = tid >> 6;
    int row = blockIdx.x * 64 + t;
    const float* rp = inputs + row * (1 + 2 * DD);
    float x[DD];
    #pragma unroll
    for (int d = 0; d < DD; ++d) x[d] = rp[1 + d];
    float m[DD], sc[DD];
    #pragma unroll
    for (int d = 0; d < DD; ++d) { m[d] = 0.0f; sc[d] = 0.0f; }

    int u0 = w * 32;
    for (int u = u0; u < u0 + 32; ++u) {
        float hv = sb1[u];
        #pragma unroll
        for (int d = 0; d < DD; ++d) hv = fmaf(x[d], sW1[d * HH + u], hv);
        hv = fmaxf(hv, 0.0f);
        #pragma unroll
        for (int d = 0; d < DD; ++d) m[d] = fmaf(hv, sWm[u * DD + d], m[d]);
        #pragma unroll
        for (int d = 0; d < DD; ++d) sc[d] = fmaf(hv, sWs[u * DD + d], sc[d]);
    }
    #pragma unroll
    for (int d = 0; d < DD; ++d) { mpart[d][tid] = m[d]; spart[d][tid] = sc[d]; }
    __syncthreads();

    if (w == 0) {
        float step = rp[0];
        float ss = sqrtf(step);
        float r2 = 0.0f;
        #pragma unroll
        for (int d = 0; d < DD; ++d) {
            float mm = mpart[d][t] + mpart[d][64 + t] + mpart[d][128 + t]
                     + mpart[d][192 + t] + bm[d];
            float sv = spart[d][t] + spart[d][64 + t] + spart[d][128 + t]
                     + spart[d][192 + t] + bs[d];
            float sp = softplus_f(sv) + 0.001f;
            float smp = (rp[1 + DD + d] - (x[d] + step * mm)) / (ss * sp);
            samples[row * DD + d] = smp;
            r2 = fmaf(smp, smp, r2);
        }
        hvals[row] = -0.5f * r2 * L2E;     // pre-scaled for base-2 exp

        float t1 = __expf(-0.25f * r2);
        #pragma unroll
        for (int off = 32; off > 0; off >>= 1) t1 += __shfl_down(t1, off);
        if (t == 0) atomicAdd(&acc[1], t1);
    }
}

// Symmetric tiling: 16 tiles of 1024 rows; blocks cover (a,b) a<=b, 8 k-chunks
// of 128 each -> 1088 blocks. Weight 2 off-diagonal, 1 on diagonal.
__global__ __launch_bounds__(256, 2) void pair_kernel(
    const float* __restrict__ samples, const float* __restrict__ hvals,
    float* __restrict__ acc)
{
    __shared__ float sk[TK * DD];
    __shared__ float shk[TK];
    int t = threadIdx.x;

    int bx = blockIdx.x;
    int p = bx >> 3, chunk = bx & 7;
    int a = 0;
    while (p >= NTILE - a) { p -= NTILE - a; ++a; }
    int b = a + p;

    float sj[JPT][DD], hj[JPT], sum[JPT];
    #pragma unroll
    for (int jj = 0; jj < JPT; ++jj) {
        int j = a * 1024 + jj * 256 + t;
        #pragma unroll
        for (int d = 0; d < DD; ++d) sj[jj][d] = samples[j * DD + d] * L2E;
        hj[jj] = hvals[j];
        sum[jj] = 0.0f;
    }
    // Pin j-fragments in VGPRs: opaque asm prevents the register allocator
    // from rematerializing the global loads inside the k-loop (R1: VGPR=52,
    // loads sunk into loop -> latency-bound at VALUBusy 70%).
    #pragma unroll
    for (int jj = 0; jj < JPT; ++jj) {
        #pragma unroll
        for (int d = 0; d < DD; ++d) asm("" : "+v"(sj[jj][d]));
        asm("" : "+v"(hj[jj]));
    }

    {
        int k0 = b * 1024 + chunk * TK;
        int r = t >> 1, h = t & 1;
        const float4* src = (const float4*)(samples + (k0 + r) * DD + h * 8);
        float4* dst = (float4*)(sk + r * DD + h * 8);
        dst[0] = src[0]; dst[1] = src[1];
        if (t < TK) shk[t] = hvals[k0 + t];
    }
    __syncthreads();

    #pragma unroll 2
    for (int kk = 0; kk < TK; ++kk) {
        float hk = shk[kk];
        const float4* sp4 = (const float4*)(sk + kk * DD);
        float4 q0 = sp4[0], q1 = sp4[1], q2 = sp4[2], q3 = sp4[3];
        float kv[16] = {q0.x, q0.y, q0.z, q0.w, q1.x, q1.y, q1.z, q1.w,
                        q2.x, q2.y, q2.z, q2.w, q3.x, q3.y, q3.z, q3.w};
        #pragma unroll
        for (int jj = 0; jj < JPT; ++jj) {
            float arg = hj[jj] + hk;
            #pragma unroll
            for (int d = 0; d < DD; ++d) arg = fmaf(sj[jj][d], kv[d], arg);
            sum[jj] += exp2_fast(arg);
        }
    }

    float v = sum[0] + sum[1] + sum[2] + sum[3];
    #pragma unroll
    for (int off = 32; off > 0; off >>= 1) v += __shfl_down(v, off);
    __shared__ float red[4];
    if ((t & 63) == 0) red[t >> 6] = v;
    __syncthreads();
    if (t == 0) {
        float w = (a == b) ? 1.0f : 2.0f;
        atomicAdd(&acc[0], w * (red[0] + red[1] + red[2] + red[3]));
    }
}

__global__ void final_kernel(const float* __restrict__ acc, float* __restrict__ out) {
    float n = (float)NROWS;
    out[0] = acc[0] / n - 0.0078125f * acc[1] + n * (1.0f / 6561.0f);
}

extern "C" void kernel_launch(void* const* d_in, const int* in_sizes, int n_in,
                              void* d_out, int out_size, void* d_ws, size_t ws_size,
                              hipStream_t stream)
{
    const float* inputs = (const float*)d_in[0];
    const float* W1 = (const float*)d_in[1];
    const float* b1 = (const float*)d_in[2];
    const float* Wm = (const float*)d_in[3];
    const float* bm = (const float*)d_in[4];
    const float* Ws = (const float*)d_in[5];
    const float* bs = (const float*)d_in[6];

    float* acc     = (float*)d_ws;
    float* hvals   = (float*)((char*)d_ws + 256);
    float* samples = (float*)((char*)d_ws + 256 + NROWS * 4);

    hipMemsetAsync(d_ws, 0, 256, stream);
    prep_kernel<<<NROWS / 64, 256, 0, stream>>>(inputs, W1, b1, Wm, bm, Ws, bs,
                                                samples, hvals, acc);
    int npairs = NTILE * (NTILE + 1) / 2;           // 136
    pair_kernel<<<npairs * CHUNKS, 256, 0, stream>>>(samples, hvals, acc);
    final_kernel<<<1, 1, 0, stream>>>(acc, (float*)d_out);
}

// Round 4
// 61.905 us; speedup vs baseline: 3.0747x; 1.6168x over previous
//
#include <hip/hip_runtime.h>
#include <math.h>

#define NROWS 16384
#define DD 16
#define HH 128
#define NSUP 64            // 64 supertiles of 256 rows
#define L2E 1.4426950408889634f
#define SQL2E 1.2011224087864498f   // sqrt(log2(e))

typedef __attribute__((ext_vector_type(8))) short v8s;   // 8 bf16 = 4 VGPR (MFMA A/B frag)
typedef __attribute__((ext_vector_type(4))) float v4f;   // MFMA C/D frag
typedef __attribute__((ext_vector_type(4))) unsigned int v4u;

__device__ __forceinline__ float softplus_f(float x) {
    return fmaxf(x, 0.0f) + log1pf(__expf(-fabsf(x)));
}
__device__ __forceinline__ float exp2_fast(float x) {
    float r;
    asm("v_exp_f32 %0, %1" : "=v"(r) : "v"(x));
    return r;
}
__device__ __forceinline__ unsigned short bf16_rne(float f) {
    unsigned int u = __float_as_uint(f);
    return (unsigned short)((u + 0x7FFFu + ((u >> 16) & 1u)) >> 16);
}

// 256 threads = 4 waves; 64 rows/block; wave w computes hidden units [w*32,(w+1)*32)
__global__ __launch_bounds__(256) void prep_kernel(
    const float* __restrict__ inputs,
    const float* __restrict__ W1, const float* __restrict__ b1,
    const float* __restrict__ Wm, const float* __restrict__ bm,
    const float* __restrict__ Ws, const float* __restrict__ bs,
    unsigned int* __restrict__ packed,   // NROWS x 16 uints: [shi bf16 x16 | slo bf16 x16]
    float* __restrict__ hvals,           // -0.5*r2*log2e
    float* __restrict__ acc)
{
    __shared__ float sW1[DD * HH], sWm[HH * DD], sWs[HH * DD];
    __shared__ float sb1[HH];
    __shared__ float mpart[DD][256], spart[DD][256];
    int tid = threadIdx.x;
    for (int i = tid; i < DD * HH; i += 256) {
        sW1[i] = W1[i]; sWm[i] = Wm[i]; sWs[i] = Ws[i];
    }
    if (tid < HH) sb1[tid] = b1[tid];
    __syncthreads();

    int t = tid & 63, w = tid >> 6;
    int row = blockIdx.x * 64 + t;
    const float* rp = inputs + row * (1 + 2 * DD);
    float x[DD];
    #pragma unroll
    for (int d = 0; d < DD; ++d) x[d] = rp[1 + d];
    float m[DD], sc[DD];
    #pragma unroll
    for (int d = 0; d < DD; ++d) { m[d] = 0.0f; sc[d] = 0.0f; }

    int u0 = w * 32;
    for (int u = u0; u < u0 + 32; ++u) {
        float hv = sb1[u];
        #pragma unroll
        for (int d = 0; d < DD; ++d) hv = fmaf(x[d], sW1[d * HH + u], hv);
        hv = fmaxf(hv, 0.0f);
        #pragma unroll
        for (int d = 0; d < DD; ++d) m[d] = fmaf(hv, sWm[u * DD + d], m[d]);
        #pragma unroll
        for (int d = 0; d < DD; ++d) sc[d] = fmaf(hv, sWs[u * DD + d], sc[d]);
    }
    #pragma unroll
    for (int d = 0; d < DD; ++d) { mpart[d][tid] = m[d]; spart[d][tid] = sc[d]; }
    __syncthreads();

    if (w == 0) {
        float step = rp[0];
        float ss = sqrtf(step);
        float r2 = 0.0f;
        float smp[DD];
        #pragma unroll
        for (int d = 0; d < DD; ++d) {
            float mm = mpart[d][t] + mpart[d][64 + t] + mpart[d][128 + t]
                     + mpart[d][192 + t] + bm[d];
            float sv = spart[d][t] + spart[d][64 + t] + spart[d][128 + t]
                     + spart[d][192 + t] + bs[d];
            float sp = softplus_f(sv) + 0.001f;
            smp[d] = (rp[1 + DD + d] - (x[d] + step * mm)) / (ss * sp);
            r2 = fmaf(smp[d], smp[d], r2);
        }
        hvals[row] = -0.5f * r2 * L2E;

        float t1 = __expf(-0.25f * r2);
        #pragma unroll
        for (int off = 32; off > 0; off >>= 1) t1 += __shfl_down(t1, off);
        if (t == 0) atomicAdd(&acc[1], t1);

        // pack: s' = s*sqrt(log2e); shi = bf16(s'), slo = bf16(s' - shi)
        unsigned short hs[DD], ls[DD];
        #pragma unroll
        for (int d = 0; d < DD; ++d) {
            float sp2 = smp[d] * SQL2E;
            unsigned short hi = bf16_rne(sp2);
            float rem = sp2 - __uint_as_float(((unsigned int)hi) << 16);
            hs[d] = hi;
            ls[d] = bf16_rne(rem);
        }
        unsigned int* prow = packed + row * 16;
        v4u q;
        q.x = hs[0] | (hs[1] << 16);  q.y = hs[2] | (hs[3] << 16);
        q.z = hs[4] | (hs[5] << 16);  q.w = hs[6] | (hs[7] << 16);
        *(v4u*)(prow + 0) = q;
        q.x = hs[8] | (hs[9] << 16);  q.y = hs[10] | (hs[11] << 16);
        q.z = hs[12] | (hs[13] << 16); q.w = hs[14] | (hs[15] << 16);
        *(v4u*)(prow + 4) = q;
        q.x = ls[0] | (ls[1] << 16);  q.y = ls[2] | (ls[3] << 16);
        q.z = ls[4] | (ls[5] << 16);  q.w = ls[6] | (ls[7] << 16);
        *(v4u*)(prow + 8) = q;
        q.x = ls[8] | (ls[9] << 16);  q.y = ls[10] | (ls[11] << 16);
        q.z = ls[12] | (ls[13] << 16); q.w = ls[14] | (ls[15] << 16);
        *(v4u*)(prow + 12) = q;
    }
}

// Symmetric supertile pairs: 64 supertiles of 256 rows, blocks (a,b) a<=b (2080).
// Each block: 4 waves x 4 j-frags of 16 rows; k supertile staged in LDS in MFMA
// fragment-lane order (linear ds_read_b128, conflict-free). Two MFMAs per tile:
// [shi|slo]x[khi|klo] + [slo|shi]x[khi|klo] = exact (shi+slo)(khi+klo).
// Diagonal (j==k) masked out; added exactly (+n) in final_kernel.
__global__ __launch_bounds__(256, 1) void pair_kernel(
    const unsigned int* __restrict__ packed,
    const float* __restrict__ hvals,
    float* __restrict__ acc)
{
    __shared__ unsigned short skB[8192];   // 16 KB: 1024 chunks of 16B, lane-ordered
    __shared__ float shk[256];
    __shared__ float red[4];

    int tid = threadIdx.x;
    int l = tid & 63, w = tid >> 6;

    int p = blockIdx.x;
    int a = 0;
    while (p >= NSUP - a) { p -= NSUP - a; ++a; }
    int b = a + p;
    bool isdiag = (a == b);

    int jbase = a * 256 + w * 64;
    int kb = b * 256;

    int col = l & 15;       // MFMA N-col / A-row selector
    int sub = l >> 4;       // K-subblock 0..3
    int myrow4 = sub * 4;   // C-row base for this lane

    // A fragments (4 per wave), direct from global (L2-resident)
    const unsigned short* pk16 = (const unsigned short*)packed;
    v8s A1[4], A2[4];
    float hjr[4][4];
    #pragma unroll
    for (int f = 0; f < 4; ++f) {
        int jrow = jbase + f * 16 + col;
        A1[f] = *(const v8s*)(pk16 + (size_t)jrow * 32 + sub * 8);
        A2[f] = *(const v8s*)(pk16 + (size_t)jrow * 32 + (sub ^ 2) * 8);
        #pragma unroll
        for (int r = 0; r < 4; ++r)
            hjr[f][r] = hvals[jbase + f * 16 + myrow4 + r];
    }

    // stage k supertile: chunk c*256+tid -> LDS chunk-linear; global addr permuted
    #pragma unroll
    for (int c = 0; c < 4; ++c) {
        int chunk = c * 256 + tid;
        int tt = chunk >> 6, l6 = chunk & 63;
        int rec = kb + tt * 16 + (l6 & 15);
        int sk = l6 >> 4;
        v8s v = *(const v8s*)(pk16 + (size_t)rec * 32 + sk * 8);
        *(v8s*)(skB + chunk * 8) = v;
    }
    shk[tid] = hvals[kb + tid];
    __syncthreads();

    float sumv = 0.0f;
    const v8s* skB8 = (const v8s*)skB;
    #pragma unroll 4
    for (int tt = 0; tt < 16; ++tt) {
        v8s B1 = skB8[tt * 64 + l];
        float hk = shk[tt * 16 + col];
        #pragma unroll
        for (int f = 0; f < 4; ++f) {
            v4f cc;
            cc[0] = hjr[f][0] + hk; cc[1] = hjr[f][1] + hk;
            cc[2] = hjr[f][2] + hk; cc[3] = hjr[f][3] + hk;
            cc = __builtin_amdgcn_mfma_f32_16x16x32_bf16(A1[f], B1, cc, 0, 0, 0);
            cc = __builtin_amdgcn_mfma_f32_16x16x32_bf16(A2[f], B1, cc, 0, 0, 0);
            float e0 = exp2_fast(cc[0]);
            float e1 = exp2_fast(cc[1]);
            float e2 = exp2_fast(cc[2]);
            float e3 = exp2_fast(cc[3]);
            if (isdiag && tt == (w * 4 + f)) {
                if (myrow4 + 0 == col) e0 = 0.0f;
                if (myrow4 + 1 == col) e1 = 0.0f;
                if (myrow4 + 2 == col) e2 = 0.0f;
                if (myrow4 + 3 == col) e3 = 0.0f;
            }
            sumv += (e0 + e1) + (e2 + e3);
        }
    }

    #pragma unroll
    for (int off = 32; off > 0; off >>= 1) sumv += __shfl_down(sumv, off);
    if (l == 0) red[w] = sumv;
    __syncthreads();
    if (tid == 0) {
        float wgt = isdiag ? 1.0f : 2.0f;
        atomicAdd(&acc[0], wgt * (red[0] + red[1] + red[2] + red[3]));
    }
}

__global__ void final_kernel(const float* __restrict__ acc, float* __restrict__ out) {
    float n = (float)NROWS;
    // +n = exact diagonal (exp(0) per row), masked out of the pair sum
    out[0] = (acc[0] + n) / n - 0.0078125f * acc[1] + n * (1.0f / 6561.0f);
}

extern "C" void kernel_launch(void* const* d_in, const int* in_sizes, int n_in,
                              void* d_out, int out_size, void* d_ws, size_t ws_size,
                              hipStream_t stream)
{
    const float* inputs = (const float*)d_in[0];
    const float* W1 = (const float*)d_in[1];
    const float* b1 = (const float*)d_in[2];
    const float* Wm = (const float*)d_in[3];
    const float* bm = (const float*)d_in[4];
    const float* Ws = (const float*)d_in[5];
    const float* bs = (const float*)d_in[6];

    float* acc           = (float*)d_ws;
    float* hvals         = (float*)((char*)d_ws + 256);
    unsigned int* packed = (unsigned int*)((char*)d_ws + 256 + NROWS * 4);  // 1 MB

    hipMemsetAsync(d_ws, 0, 256, stream);
    prep_kernel<<<NROWS / 64, 256, 0, stream>>>(inputs, W1, b1, Wm, bm, Ws, bs,
                                                packed, hvals, acc);
    int npairs = NSUP * (NSUP + 1) / 2;     // 2080
    pair_kernel<<<npairs, 256, 0, stream>>>(packed, hvals, acc);
    final_kernel<<<1, 1, 0, stream>>>(acc, (float*)d_out);
}